// Round 15
// baseline (7400.120 us; speedup 1.0000x reference)
//
#include <hip/hip_runtime.h>
#include <cstdint>
#include <cstddef>

typedef _Float16 f16;
typedef _Float16 f16x8 __attribute__((ext_vector_type(8)));
typedef _Float16 f16x4v __attribute__((ext_vector_type(4)));
typedef float f32x4 __attribute__((ext_vector_type(4)));
typedef unsigned uint2v __attribute__((ext_vector_type(2)));

#define TT 2048
#define BB 16
#define DD 1024
#define MM (TT*BB)
#define FPAD 16   // flag padding: one flag per 64B line
#define NFIN 192  // persistent fin-GEMM worker blocks

#define AS1 __attribute__((address_space(1)))
#define AS3 __attribute__((address_space(3)))

// ---------------- f32 -> f16 convert (single buffer) ----------------
__global__ void cvt_kernel(const float* __restrict__ in, f16* __restrict__ out, int n4){
  int stride = gridDim.x * blockDim.x;
  for (int j = blockIdx.x*blockDim.x + threadIdx.x; j < n4; j += stride){
    float4 v = ((const float4*)in)[j];
    f16x4v o;
    o[0]=(f16)v.x; o[1]=(f16)v.y; o[2]=(f16)v.z; o[3]=(f16)v.w;
    ((f16x4v*)out)[j] = o;
  }
}

// ---------------- fused f32->f16 convert for the 5 DxD weights ----------------
__global__ void cvt5_kernel(const float* __restrict__ a0, const float* __restrict__ a1,
                            const float* __restrict__ a2, const float* __restrict__ a3,
                            const float* __restrict__ a4,
                            f16* __restrict__ o0, f16* __restrict__ o1,
                            f16* __restrict__ o2, f16* __restrict__ o3, f16* __restrict__ o4){
  const float* src[5] = {a0,a1,a2,a3,a4};
  f16* dst[5] = {o0,o1,o2,o3,o4};
  int which = blockIdx.y;
  const float* in = src[which];
  f16* out = dst[which];
  int j = blockIdx.x*blockDim.x + threadIdx.x;
  float4 v = ((const float4*)in)[j];
  f16x4v o;
  o[0]=(f16)v.x; o[1]=(f16)v.y; o[2]=(f16)v.z; o[3]=(f16)v.w;
  ((f16x4v*)out)[j] = o;
}

// ---------------- init: zero flags + gstep + work counter, h0 -> hbuf[0] ----------------
__global__ void init_rec_kernel(const float* __restrict__ h0, f16* __restrict__ hbuf,
                                unsigned* __restrict__ flags){
  int tid = blockIdx.x*blockDim.x + threadIdx.x;
  if (tid < 64*FPAD + 64) flags[tid] = 0u;   // flags + gstep + wcnt region
  if (tid < BB*DD) hbuf[tid] = (f16)h0[tid];
}

// ======== shared GEMM tile machinery for gemm_wa (128x128, f16 MFMA, B=[N,K]) ========
#define GEMM_PROLOGUE() \
  __shared__ f16 As[128*32]; \
  __shared__ f16 Bs[128*32]; \
  int tid = threadIdx.x; \
  int l = tid & 63, w = tid >> 6; \
  int wr = w >> 1, wc = w & 1; \
  f32x4 acc[4][4]; \
  _Pragma("unroll") for (int i=0;i<4;++i) _Pragma("unroll") for (int jj=0;jj<4;++jj) \
    acc[i][jj] = (f32x4){0.f,0.f,0.f,0.f};

#define GEMM_KSTEP(Asrc, Bsrc, ktl) { \
  __syncthreads(); \
  _Pragma("unroll") for (int hh=0; hh<2; ++hh){ \
    int r = hh*64 + (tid>>2); \
    int q = (tid&3) ^ (r&3); \
    const f16* ga = (Asrc) + (size_t)(bm*128+r)*DD + (ktl)*32 + q*8; \
    const f16* gb = (Bsrc) + (size_t)(bcol*128+r)*DD + (ktl)*32 + q*8; \
    __builtin_amdgcn_global_load_lds((AS1 void*)ga, (AS3 void*)(As + hh*2048 + tid*8), 16, 0, 0); \
    __builtin_amdgcn_global_load_lds((AS1 void*)gb, (AS3 void*)(Bs + hh*2048 + tid*8), 16, 0, 0); \
  } \
  __syncthreads(); \
  int lr = l & 15, g = l >> 4; \
  f16x8 af[4], bf[4]; \
  _Pragma("unroll") for (int i=0;i<4;++i){ \
    int Ra = wr*64 + i*16 + lr; \
    int Rb = wc*64 + i*16 + lr; \
    af[i] = *(const f16x8*)(As + Ra*32 + ((g ^ (Ra & 3)) * 8)); \
    bf[i] = *(const f16x8*)(Bs + Rb*32 + ((g ^ (Rb & 3)) * 8)); \
  } \
  _Pragma("unroll") for (int i=0;i<4;++i) \
    _Pragma("unroll") for (int jj=0;jj<4;++jj) \
      acc[i][jj] = __builtin_amdgcn_mfma_f32_16x16x32_f16(af[i], bf[jj], acc[i][jj], 0,0,0); \
}

// ---------------- fused wx + alpha GEMM: grid (MM/128, 16) ----------------
__global__ __launch_bounds__(256)
void gemm_wa_kernel(const f16* __restrict__ x16,
                    const f16* __restrict__ Wx16, const f16* __restrict__ Wd16,
                    f16* __restrict__ wxo, f16* __restrict__ alo,
                    const float* __restrict__ bias, const float* __restrict__ bd,
                    const float* __restrict__ Aar)
{
  int bm = blockIdx.x, bn = blockIdx.y;
  int alpha_path = (bn >= 8);
  int bcol = bn & 7;
  const f16* Bw = alpha_path ? Wd16 : Wx16;

  GEMM_PROLOGUE();
  for (int kt = 0; kt < 32; ++kt) GEMM_KSTEP(x16, Bw, kt);

  int lr = l & 15, lh = l >> 4;
  #pragma unroll
  for (int i=0;i<4;++i){
    #pragma unroll
    for (int jj=0;jj<4;++jj){
      #pragma unroll
      for (int r=0;r<4;++r){
        int row = bm*128 + wr*64 + i*16 + lh*4 + r;
        int col = bcol*128 + wc*64 + jj*16 + lr;
        float v = acc[i][jj][r];
        size_t off = (size_t)row*DD + col;
        if (!alpha_path){
          wxo[off] = (f16)(v + bias[col]);
        } else {
          float pre = v + bd[col];
          float sp  = (pre > 20.f) ? pre : log1pf(expf(pre));
          float decay = expf(-expf(Aar[col]));
          alo[off] = (f16)expf(-sp*decay);
        }
      }
    }
  }
}

// ================= merged recurrence + streaming final GEMM =================
// blocks 0..63: rec role (wave0 only; proven R8/R12 protocol; hout via sc0sc1 pre-drain;
//   slice0 publishes gstep = t after each acquire; gstep=2048 after final flag poll).
// blocks 64..64+NFIN-1: persistent fin workers: grab tile g from wcnt (atomicAdd);
//   bm=g>>3, bcol=g&7; wait gstep >= (bm+1)*8; C = hout@Wgh^T + x@Wgx^T;
//   out = hout * silu(C + bg). hout read ONLY via sc0sc1 (no kernel boundary).
__global__ __launch_bounds__(256)
void recfin_kernel(const f16* __restrict__ Rf, const f16* __restrict__ wx,
                   const f16* __restrict__ alpha, const float* __restrict__ h0,
                   f16* __restrict__ hbuf, f16* __restrict__ hout,
                   unsigned* __restrict__ flags, unsigned* __restrict__ gstep,
                   unsigned* __restrict__ wcnt,
                   const f16* __restrict__ x16, const f16* __restrict__ Wgh16,
                   const f16* __restrict__ Wgx16, float* __restrict__ out,
                   const float* __restrict__ bg)
{
  __shared__ __align__(16) char smem[32768];
  __shared__ unsigned tilevar;

  if (blockIdx.x < 64){
    // ---------------- rec role (single wave) ----------------
    if (threadIdx.x >= 64) return;
    f16* Rlds = (f16*)smem;
    int l = threadIdx.x;
    int j = blockIdx.x;
    int e0 = j * 16;

    #pragma unroll
    for (int kt=0; kt<32; ++kt){
      int e = e0 + (l & 15);
      int d = kt*32 + (l >> 4)*8;
      *(uint4*)(Rlds + ((size_t)kt*64 + l)*8) = *(const uint4*)(Rf + (size_t)e*DD + d);
    }
    asm volatile("s_waitcnt lgkmcnt(0)" ::: "memory");
    __builtin_amdgcn_sched_barrier(0);

    int b = l & 15, rr0 = (l >> 4) * 4;
    float4 hstate = *(const float4*)(h0 + (size_t)b*DD + e0 + rr0);

    f32x4 wxv, alv;
    {
      f16x4v wh = *(const f16x4v*)(wx + (size_t)b*DD + e0 + rr0);
      f16x4v ah = *(const f16x4v*)(alpha + (size_t)b*DD + e0 + rr0);
      #pragma unroll
      for (int r=0;r<4;++r){ wxv[r] = (float)wh[r]; alv[r] = (float)ah[r]; }
    }

    for (int t = 0; t < TT; ++t){
      if (t > 0){
        const unsigned* fp = flags + l*FPAD;
        int guard = 0;
        unsigned long long notready = 1ull;
        while (notready && guard < 2000000){
          unsigned fv = __hip_atomic_load(fp, __ATOMIC_RELAXED, __HIP_MEMORY_SCOPE_AGENT);
          notready = __ballot(fv < (unsigned)t);
          ++guard;
          if (notready && guard > 16) __builtin_amdgcn_s_sleep(1);
        }
        // slice0 publishes aggregated progress: all flags >= t observed
        if (j == 0 && l == 0)
          __hip_atomic_store(gstep, (unsigned)t, __ATOMIC_RELAXED, __HIP_MEMORY_SCOPE_AGENT);
      }

      const f16* hb = hbuf + (size_t)(t & 1) * (BB*DD);
      f16x8 hfr[32];
      #pragma unroll
      for (int kt=0; kt<32; ++kt){
        const f16* hp = hb + (size_t)b*DD + kt*32 + (l >> 4)*8;
        asm volatile("global_load_dwordx4 %0, %1, off sc0 sc1"
                     : "=v"(hfr[kt]) : "v"(hp) : "memory");
      }

      f32x4 accv[4];
      #pragma unroll
      for (int c=0;c<4;++c) accv[c] = (f32x4){0.f,0.f,0.f,0.f};

      asm volatile("s_waitcnt vmcnt(24)" ::: "memory");
      __builtin_amdgcn_sched_barrier(0);
      #pragma unroll
      for (int kt=0; kt<8; ++kt){
        f16x8 a = *(const f16x8*)(Rlds + ((size_t)kt*64 + l)*8);
        accv[kt&3] = __builtin_amdgcn_mfma_f32_16x16x32_f16(a, hfr[kt], accv[kt&3], 0, 0, 0);
      }
      asm volatile("s_waitcnt vmcnt(16)" ::: "memory");
      __builtin_amdgcn_sched_barrier(0);
      #pragma unroll
      for (int kt=8; kt<16; ++kt){
        f16x8 a = *(const f16x8*)(Rlds + ((size_t)kt*64 + l)*8);
        accv[kt&3] = __builtin_amdgcn_mfma_f32_16x16x32_f16(a, hfr[kt], accv[kt&3], 0, 0, 0);
      }
      asm volatile("s_waitcnt vmcnt(8)" ::: "memory");
      __builtin_amdgcn_sched_barrier(0);

      int tn = (t+1 < TT) ? (t+1) : t;
      size_t offn = ((size_t)tn*BB + b)*DD + e0 + rr0;
      f16x4v whn = *(const f16x4v*)(wx + offn);
      f16x4v ahn = *(const f16x4v*)(alpha + offn);

      #pragma unroll
      for (int kt=16; kt<24; ++kt){
        f16x8 a = *(const f16x8*)(Rlds + ((size_t)kt*64 + l)*8);
        accv[kt&3] = __builtin_amdgcn_mfma_f32_16x16x32_f16(a, hfr[kt], accv[kt&3], 0, 0, 0);
      }
      asm volatile("s_waitcnt vmcnt(0)" ::: "memory");
      __builtin_amdgcn_sched_barrier(0);
      #pragma unroll
      for (int kt=24; kt<32; ++kt){
        f16x8 a = *(const f16x8*)(Rlds + ((size_t)kt*64 + l)*8);
        accv[kt&3] = __builtin_amdgcn_mfma_f32_16x16x32_f16(a, hfr[kt], accv[kt&3], 0, 0, 0);
      }
      f32x4 acc = (accv[0]+accv[1]) + (accv[2]+accv[3]);

      f16x4v h4;
      float hs[4] = {hstate.x, hstate.y, hstate.z, hstate.w};
      #pragma unroll
      for (int r=0;r<4;++r){
        float z = acc[r] + wxv[r];
        float cand = tanhf(z);
        float hn = alv[r]*hs[r] + (1.f - alv[r])*cand;
        hs[r] = hn;
        h4[r] = (f16)hn;
      }
      hstate = (float4){hs[0], hs[1], hs[2], hs[3]};

      // release: h store + hout store (both sc0sc1) -> joint drain -> flag publish
      f16* hw = hbuf + (size_t)((t+1) & 1) * (BB*DD) + (size_t)b*DD + e0 + rr0;
      uint2v hv = __builtin_bit_cast(uint2v, h4);
      asm volatile("global_store_dwordx2 %0, %1, off sc0 sc1"
                   :: "v"(hw), "v"(hv) : "memory");
      f16* hop = hout + ((size_t)t*BB + b)*DD + e0 + rr0;
      asm volatile("global_store_dwordx2 %0, %1, off sc0 sc1"
                   :: "v"(hop), "v"(hv) : "memory");
      asm volatile("s_waitcnt vmcnt(0)" ::: "memory");
      if (l == 0)
        __hip_atomic_store(flags + j*FPAD, (unsigned)(t+1),
                           __ATOMIC_RELAXED, __HIP_MEMORY_SCOPE_AGENT);

      #pragma unroll
      for (int r=0;r<4;++r){ wxv[r] = (float)whn[r]; alv[r] = (float)ahn[r]; }
    }

    // slice0: wait all flags == 2048, then publish gstep = 2048 (covers last fin tiles)
    if (j == 0){
      const unsigned* fp = flags + l*FPAD;
      int guard = 0;
      unsigned long long notready = 1ull;
      while (notready && guard < 2000000){
        unsigned fv = __hip_atomic_load(fp, __ATOMIC_RELAXED, __HIP_MEMORY_SCOPE_AGENT);
        notready = __ballot(fv < 2048u);
        ++guard;
        if (notready) __builtin_amdgcn_s_sleep(1);
      }
      if (l == 0)
        __hip_atomic_store(gstep, 2048u, __ATOMIC_RELAXED, __HIP_MEMORY_SCOPE_AGENT);
    }
    return;
  }

  // ---------------- fin role: persistent worker ----------------
  f16* As = (f16*)smem;
  f16* Bs = (f16*)(smem + 8192);
  int tid = threadIdx.x;
  int l = tid & 63, w = tid >> 6;
  int wr = w >> 1, wc = w & 1;
  int lr = l & 15, lh = l >> 4;

  for (;;){
    if (tid == 0) tilevar = atomicAdd(wcnt, 1u);
    __syncthreads();
    unsigned g = tilevar;
    __syncthreads();
    if (g >= 2048u) break;
    int bm = (int)(g >> 3), bcol = (int)(g & 7);

    // gate: need all hout rows < (bm+1)*8 published
    if (tid == 0){
      unsigned need = (unsigned)((bm + 1) * 8);
      int guard = 0;
      while (guard < 1000000){
        unsigned gs = __hip_atomic_load(gstep, __ATOMIC_RELAXED, __HIP_MEMORY_SCOPE_AGENT);
        if (gs >= need) break;
        ++guard;
        __builtin_amdgcn_s_sleep(32);
      }
    }
    __syncthreads();

    f32x4 acc[4][4];
    #pragma unroll
    for (int i=0;i<4;++i)
      #pragma unroll
      for (int jj=0;jj<4;++jj)
        acc[i][jj] = (f32x4){0.f,0.f,0.f,0.f};

    // phase 1: A = hout (reg-staged, sc0sc1), B = Wgh (global_load_lds)
    for (int kt = 0; kt < 32; ++kt){
      __syncthreads();
      int r0_ = tid >> 2,        q0 = (tid & 3) ^ (r0_ & 3);
      int r1_ = 64 + (tid >> 2), q1 = (tid & 3) ^ (r1_ & 3);
      f16x8 va0, va1;
      const f16* ga0 = hout + (size_t)(bm*128 + r0_)*DD + kt*32 + q0*8;
      const f16* ga1 = hout + (size_t)(bm*128 + r1_)*DD + kt*32 + q1*8;
      asm volatile("global_load_dwordx4 %0, %1, off sc0 sc1" : "=v"(va0) : "v"(ga0) : "memory");
      asm volatile("global_load_dwordx4 %0, %1, off sc0 sc1" : "=v"(va1) : "v"(ga1) : "memory");
      const f16* gb0 = Wgh16 + (size_t)(bcol*128 + r0_)*DD + kt*32 + q0*8;
      const f16* gb1 = Wgh16 + (size_t)(bcol*128 + r1_)*DD + kt*32 + q1*8;
      __builtin_amdgcn_global_load_lds((AS1 void*)gb0, (AS3 void*)(Bs + tid*8), 16, 0, 0);
      __builtin_amdgcn_global_load_lds((AS1 void*)gb1, (AS3 void*)(Bs + 2048 + tid*8), 16, 0, 0);
      asm volatile("s_waitcnt vmcnt(0)" ::: "memory");
      __builtin_amdgcn_sched_barrier(0);
      *(f16x8*)(As + tid*8) = va0;
      *(f16x8*)(As + 2048 + tid*8) = va1;
      __syncthreads();
      f16x8 af[4], bf[4];
      #pragma unroll
      for (int i=0;i<4;++i){
        int Ra = wr*64 + i*16 + lr;
        int Rb = wc*64 + i*16 + lr;
        af[i] = *(const f16x8*)(As + Ra*32 + ((lh ^ (Ra & 3)) * 8));
        bf[i] = *(const f16x8*)(Bs + Rb*32 + ((lh ^ (Rb & 3)) * 8));
      }
      #pragma unroll
      for (int i=0;i<4;++i)
        #pragma unroll
        for (int jj=0;jj<4;++jj)
          acc[i][jj] = __builtin_amdgcn_mfma_f32_16x16x32_f16(af[i], bf[jj], acc[i][jj], 0,0,0);
    }

    // phase 2: A = x16, B = Wgx (both global_load_lds, plain cached)
    for (int kt = 0; kt < 32; ++kt){
      __syncthreads();
      #pragma unroll
      for (int hh=0; hh<2; ++hh){
        int r = hh*64 + (tid>>2);
        int q = (tid&3) ^ (r&3);
        const f16* ga = x16   + (size_t)(bm*128+r)*DD + kt*32 + q*8;
        const f16* gb = Wgx16 + (size_t)(bcol*128+r)*DD + kt*32 + q*8;
        __builtin_amdgcn_global_load_lds((AS1 void*)ga, (AS3 void*)(As + hh*2048 + tid*8), 16, 0, 0);
        __builtin_amdgcn_global_load_lds((AS1 void*)gb, (AS3 void*)(Bs + hh*2048 + tid*8), 16, 0, 0);
      }
      __syncthreads();
      f16x8 af[4], bf[4];
      #pragma unroll
      for (int i=0;i<4;++i){
        int Ra = wr*64 + i*16 + lr;
        int Rb = wc*64 + i*16 + lr;
        af[i] = *(const f16x8*)(As + Ra*32 + ((lh ^ (Ra & 3)) * 8));
        bf[i] = *(const f16x8*)(Bs + Rb*32 + ((lh ^ (Rb & 3)) * 8));
      }
      #pragma unroll
      for (int i=0;i<4;++i)
        #pragma unroll
        for (int jj=0;jj<4;++jj)
          acc[i][jj] = __builtin_amdgcn_mfma_f32_16x16x32_f16(af[i], bf[jj], acc[i][jj], 0,0,0);
    }

    // epilogue: hout values via sc0sc1 scalar loads (issued as a burst, one drain)
    unsigned hvr[4][4][4];
    #pragma unroll
    for (int i=0;i<4;++i)
      #pragma unroll
      for (int jj=0;jj<4;++jj)
        #pragma unroll
        for (int r=0;r<4;++r){
          const f16* hp = hout + (size_t)(bm*128 + wr*64 + i*16 + lh*4 + r)*DD
                               + bcol*128 + wc*64 + jj*16 + lr;
          asm volatile("global_load_ushort %0, %1, off sc0 sc1"
                       : "=v"(hvr[i][jj][r]) : "v"(hp) : "memory");
        }
    asm volatile("s_waitcnt vmcnt(0)" ::: "memory");
    __builtin_amdgcn_sched_barrier(0);

    #pragma unroll
    for (int i=0;i<4;++i){
      #pragma unroll
      for (int jj=0;jj<4;++jj){
        #pragma unroll
        for (int r=0;r<4;++r){
          int row = bm*128 + wr*64 + i*16 + lh*4 + r;
          int col = bcol*128 + wc*64 + jj*16 + lr;
          float gg = acc[i][jj][r] + bg[col];
          unsigned short us = (unsigned short)hvr[i][jj][r];
          float hval = (float)__builtin_bit_cast(f16, us);
          out[(size_t)row*DD + col] = hval * gg / (1.f + expf(-gg));
        }
      }
    }
  }
}

// ---------------- host launcher ----------------
extern "C" void kernel_launch(void* const* d_in, const int* in_sizes, int n_in,
                              void* d_out, int out_size, void* d_ws, size_t ws_size,
                              hipStream_t stream)
{
  const float* x    = (const float*)d_in[0];
  const float* h0   = (const float*)d_in[1];
  const float* Wx   = (const float*)d_in[2];
  const float* R    = (const float*)d_in[3];
  const float* bias = (const float*)d_in[4];
  const float* Wd   = (const float*)d_in[5];
  const float* bd   = (const float*)d_in[6];
  const float* Aar  = (const float*)d_in[7];
  const float* Wgx  = (const float*)d_in[8];
  const float* Wgh  = (const float*)d_in[9];
  const float* bg   = (const float*)d_in[10];
  float* out = (float*)d_out;

  char* ws = (char*)d_ws;
  size_t off = 0;
  auto carve = [&](size_t bytes) -> void* {
    void* p = ws + off;
    off += (bytes + 255) & ~(size_t)255;
    return p;
  };
  f16* x16    = (f16*)carve((size_t)MM*DD*2);
  f16* Wx16   = (f16*)carve((size_t)DD*DD*2);
  f16* Wd16   = (f16*)carve((size_t)DD*DD*2);
  f16* Wgx16  = (f16*)carve((size_t)DD*DD*2);
  f16* Wgh16  = (f16*)carve((size_t)DD*DD*2);
  f16* R16    = (f16*)carve((size_t)DD*DD*2);
  f16* wx16   = (f16*)carve((size_t)MM*DD*2);
  f16* al16   = (f16*)carve((size_t)MM*DD*2);
  f16* hout16 = (f16*)carve((size_t)MM*DD*2);
  f16* hbuf   = (f16*)carve((size_t)2*BB*DD*2);
  unsigned* flags = (unsigned*)carve((64*FPAD + 64)*4);
  unsigned* gstep = flags + 64*FPAD;        // own 64B line
  unsigned* wcnt  = flags + 64*FPAD + 32;   // separate line
  if (off > ws_size) return;

  cvt_kernel<<<1024, 256, 0, stream>>>(x, x16, MM*DD/4);
  dim3 g5(DD*DD/4/256, 5);
  cvt5_kernel<<<g5, 256, 0, stream>>>(Wx, Wd, Wgx, Wgh, R,
                                      Wx16, Wd16, Wgx16, Wgh16, R16);
  init_rec_kernel<<<64, 256, 0, stream>>>(h0, hbuf, flags);

  dim3 gwa(MM/128, 16);
  gemm_wa_kernel<<<gwa, 256, 0, stream>>>(x16, Wx16, Wd16, wx16, al16, bias, bd, Aar);

  recfin_kernel<<<64 + NFIN, 256, 0, stream>>>(R16, wx16, al16, h0, hbuf, hout16,
                                               flags, gstep, wcnt,
                                               x16, Wgh16, Wgx16, out, bg);
}

// Round 16
// 6995.264 us; speedup vs baseline: 1.0579x; 1.0579x over previous
//
#include <hip/hip_runtime.h>
#include <cstdint>
#include <cstddef>

typedef _Float16 f16;
typedef _Float16 f16x8 __attribute__((ext_vector_type(8)));
typedef _Float16 f16x4v __attribute__((ext_vector_type(4)));
typedef float f32x4 __attribute__((ext_vector_type(4)));
typedef unsigned uint2v __attribute__((ext_vector_type(2)));

#define TT 2048
#define BB 16
#define DD 1024
#define MM (TT*BB)
#define FPAD 16   // flag padding: one flag per 64B line

#define AS1 __attribute__((address_space(1)))
#define AS3 __attribute__((address_space(3)))

// ---------------- f32 -> f16 convert (single buffer) ----------------
__global__ void cvt_kernel(const float* __restrict__ in, f16* __restrict__ out, int n4){
  int stride = gridDim.x * blockDim.x;
  for (int j = blockIdx.x*blockDim.x + threadIdx.x; j < n4; j += stride){
    float4 v = ((const float4*)in)[j];
    f16x4v o;
    o[0]=(f16)v.x; o[1]=(f16)v.y; o[2]=(f16)v.z; o[3]=(f16)v.w;
    ((f16x4v*)out)[j] = o;
  }
}

// ---------------- fused f32->f16 convert for the 5 DxD weights ----------------
__global__ void cvt5_kernel(const float* __restrict__ a0, const float* __restrict__ a1,
                            const float* __restrict__ a2, const float* __restrict__ a3,
                            const float* __restrict__ a4,
                            f16* __restrict__ o0, f16* __restrict__ o1,
                            f16* __restrict__ o2, f16* __restrict__ o3, f16* __restrict__ o4){
  const float* src[5] = {a0,a1,a2,a3,a4};
  f16* dst[5] = {o0,o1,o2,o3,o4};
  int which = blockIdx.y;
  const float* in = src[which];
  f16* out = dst[which];
  int j = blockIdx.x*blockDim.x + threadIdx.x;
  float4 v = ((const float4*)in)[j];
  f16x4v o;
  o[0]=(f16)v.x; o[1]=(f16)v.y; o[2]=(f16)v.z; o[3]=(f16)v.w;
  ((f16x4v*)out)[j] = o;
}

// ---------------- recurrence init: zero flags, h0 -> hbuf[0] ----------------
__global__ void init_rec_kernel(const float* __restrict__ h0, f16* __restrict__ hbuf,
                                unsigned* __restrict__ flags){
  int tid = blockIdx.x*blockDim.x + threadIdx.x;
  if (tid < 64*FPAD) flags[tid] = 0u;
  if (tid < BB*DD) hbuf[tid] = (f16)h0[tid];
}

// ======== shared GEMM tile machinery (128x128, f16 MFMA, B given as [N,K]) ========
// Staging: global_load_lds width=16, LINEAR LDS dest (tid*16B), chunk-XOR swizzle applied
// on BOTH sides (rule #21): global chunk q = c ^ (r&3) feeds stored chunk c; fragment
// reads use stored chunk (g ^ (row&3)). Tile = 128 rows x 32 halves = 8KB, 2 issues/thread.
#define GEMM_PROLOGUE() \
  __shared__ f16 As[128*32]; \
  __shared__ f16 Bs[128*32]; \
  int tid = threadIdx.x; \
  int l = tid & 63, w = tid >> 6; \
  int wr = w >> 1, wc = w & 1; \
  f32x4 acc[4][4]; \
  _Pragma("unroll") for (int i=0;i<4;++i) _Pragma("unroll") for (int jj=0;jj<4;++jj) \
    acc[i][jj] = (f32x4){0.f,0.f,0.f,0.f};

#define GEMM_KSTEP(Asrc, Bsrc, ktl) { \
  __syncthreads(); \
  _Pragma("unroll") for (int hh=0; hh<2; ++hh){ \
    int r = hh*64 + (tid>>2); \
    int q = (tid&3) ^ (r&3); \
    const f16* ga = (Asrc) + (size_t)(bm*128+r)*DD + (ktl)*32 + q*8; \
    const f16* gb = (Bsrc) + (size_t)(bcol*128+r)*DD + (ktl)*32 + q*8; \
    __builtin_amdgcn_global_load_lds((AS1 void*)ga, (AS3 void*)(As + hh*2048 + tid*8), 16, 0, 0); \
    __builtin_amdgcn_global_load_lds((AS1 void*)gb, (AS3 void*)(Bs + hh*2048 + tid*8), 16, 0, 0); \
  } \
  __syncthreads(); \
  int lr = l & 15, g = l >> 4; \
  f16x8 af[4], bf[4]; \
  _Pragma("unroll") for (int i=0;i<4;++i){ \
    int Ra = wr*64 + i*16 + lr; \
    int Rb = wc*64 + i*16 + lr; \
    af[i] = *(const f16x8*)(As + Ra*32 + ((g ^ (Ra & 3)) * 8)); \
    bf[i] = *(const f16x8*)(Bs + Rb*32 + ((g ^ (Rb & 3)) * 8)); \
  } \
  _Pragma("unroll") for (int i=0;i<4;++i) \
    _Pragma("unroll") for (int jj=0;jj<4;++jj) \
      acc[i][jj] = __builtin_amdgcn_mfma_f32_16x16x32_f16(af[i], bf[jj], acc[i][jj], 0,0,0); \
}

// ---------------- fused wx + alpha GEMM: grid (MM/128, 16) ----------------
// bn<8: wx = x@Wx^T + bias -> f16 ; bn>=8: alpha = exp(-softplus(x@Wd^T+bd)*exp(-exp(A))) -> f16
__global__ __launch_bounds__(256)
void gemm_wa_kernel(const f16* __restrict__ x16,
                    const f16* __restrict__ Wx16, const f16* __restrict__ Wd16,
                    f16* __restrict__ wxo, f16* __restrict__ alo,
                    const float* __restrict__ bias, const float* __restrict__ bd,
                    const float* __restrict__ Aar)
{
  int bm = blockIdx.x, bn = blockIdx.y;
  int alpha_path = (bn >= 8);
  int bcol = bn & 7;
  const f16* Bw = alpha_path ? Wd16 : Wx16;

  GEMM_PROLOGUE();
  for (int kt = 0; kt < 32; ++kt) GEMM_KSTEP(x16, Bw, kt);

  int lr = l & 15, lh = l >> 4;
  #pragma unroll
  for (int i=0;i<4;++i){
    #pragma unroll
    for (int jj=0;jj<4;++jj){
      #pragma unroll
      for (int r=0;r<4;++r){
        int row = bm*128 + wr*64 + i*16 + lh*4 + r;
        int col = bcol*128 + wc*64 + jj*16 + lr;
        float v = acc[i][jj][r];
        size_t off = (size_t)row*DD + col;
        if (!alpha_path){
          wxo[off] = (f16)(v + bias[col]);
        } else {
          float pre = v + bd[col];
          float sp  = (pre > 20.f) ? pre : log1pf(expf(pre));
          float decay = expf(-expf(Aar[col]));
          alo[off] = (f16)expf(-sp*decay);
        }
      }
    }
  }
}

// ---------------- fused final GEMM (K=2048): out = hout * silu(hout@Wgh^T + x@Wgx^T + bg) ----
__global__ __launch_bounds__(256)
void gemm_fin_kernel(const f16* __restrict__ hout16, const f16* __restrict__ x16,
                     const f16* __restrict__ Wgh16, const f16* __restrict__ Wgx16,
                     float* __restrict__ out, const float* __restrict__ bg)
{
  int bm = blockIdx.x, bcol = blockIdx.y;

  GEMM_PROLOGUE();
  for (int kt = 0; kt < 32; ++kt) GEMM_KSTEP(hout16, Wgh16, kt);
  for (int kt = 0; kt < 32; ++kt) GEMM_KSTEP(x16,    Wgx16, kt);

  int lr = l & 15, lh = l >> 4;
  #pragma unroll
  for (int i=0;i<4;++i){
    #pragma unroll
    for (int jj=0;jj<4;++jj){
      #pragma unroll
      for (int r=0;r<4;++r){
        int row = bm*128 + wr*64 + i*16 + lh*4 + r;
        int col = bcol*128 + wc*64 + jj*16 + lr;
        float g = acc[i][jj][r] + bg[col];
        size_t off = (size_t)row*DD + col;
        float hval = (float)hout16[off];
        out[off] = hval * g / (1.f + expf(-g));
      }
    }
  }
}

// ---------------- recurrence: 64 autonomous single-wave WGs (proven R8/R12 protocol) ----
// release = 8B sc0sc1 store/lane -> vmcnt(0) -> lane0 flag store (AGENT atomic);
// acquire = lane l polls flags[l*FPAD] until all >= t (ballot) -> sc0sc1 h loads.
// Spin reverted to sleep-every-iteration (R13/R14 A/B: hot-spin was ~20us worse).
__global__ __launch_bounds__(64)
void rec_kernel(const f16* __restrict__ Rf, const f16* __restrict__ wx,
                const f16* __restrict__ alpha, const float* __restrict__ h0,
                f16* __restrict__ hbuf, f16* __restrict__ hout,
                unsigned* __restrict__ flags)
{
  __shared__ f16 Rlds[32*64*8];   // 32KB, frag-ordered: chunk c = kt*64+lane, 8 halves each

  int l = threadIdx.x;             // 0..63 (one wave per WG)
  int j = blockIdx.x;              // slice id 0..63
  int e0 = j * 16;

  #pragma unroll
  for (int kt=0; kt<32; ++kt){
    int e = e0 + (l & 15);
    int d = kt*32 + (l >> 4)*8;
    *(uint4*)(Rlds + ((size_t)kt*64 + l)*8) = *(const uint4*)(Rf + (size_t)e*DD + d);
  }

  int b = l & 15, rr0 = (l >> 4) * 4;
  float4 hstate = *(const float4*)(h0 + (size_t)b*DD + e0 + rr0);
  __syncthreads();

  f32x4 wxv, alv;
  {
    f16x4v wh = *(const f16x4v*)(wx + (size_t)b*DD + e0 + rr0);
    f16x4v ah = *(const f16x4v*)(alpha + (size_t)b*DD + e0 + rr0);
    #pragma unroll
    for (int r=0;r<4;++r){ wxv[r] = (float)wh[r]; alv[r] = (float)ah[r]; }
  }

  for (int t = 0; t < TT; ++t){
    if (t > 0){
      const unsigned* fp = flags + l*FPAD;
      int guard = 0;
      unsigned long long notready = 1ull;
      while (notready && guard < 2000000){
        unsigned fv = __hip_atomic_load(fp, __ATOMIC_RELAXED, __HIP_MEMORY_SCOPE_AGENT);
        notready = __ballot(fv < (unsigned)t);
        ++guard;
        if (notready) __builtin_amdgcn_s_sleep(1);
      }
    }

    // coherent single-shot load of this lane's full h K-slice (bypass stale caches)
    const f16* hb = hbuf + (size_t)(t & 1) * (BB*DD);
    f16x8 hfr[32];
    #pragma unroll
    for (int kt=0; kt<32; ++kt){
      const f16* hp = hb + (size_t)b*DD + kt*32 + (l >> 4)*8;
      asm volatile("global_load_dwordx4 %0, %1, off sc0 sc1"
                   : "=v"(hfr[kt]) : "v"(hp) : "memory");
    }

    f32x4 accv[4];
    #pragma unroll
    for (int c=0;c<4;++c) accv[c] = (f32x4){0.f,0.f,0.f,0.f};

    // 4-way split wait: overlap h-load tail with MFMA in 8-MFMA chunks
    asm volatile("s_waitcnt vmcnt(24)" ::: "memory");
    __builtin_amdgcn_sched_barrier(0);
    #pragma unroll
    for (int kt=0; kt<8; ++kt){
      f16x8 a = *(const f16x8*)(Rlds + ((size_t)kt*64 + l)*8);
      accv[kt&3] = __builtin_amdgcn_mfma_f32_16x16x32_f16(a, hfr[kt], accv[kt&3], 0, 0, 0);
    }
    asm volatile("s_waitcnt vmcnt(16)" ::: "memory");
    __builtin_amdgcn_sched_barrier(0);
    #pragma unroll
    for (int kt=8; kt<16; ++kt){
      f16x8 a = *(const f16x8*)(Rlds + ((size_t)kt*64 + l)*8);
      accv[kt&3] = __builtin_amdgcn_mfma_f32_16x16x32_f16(a, hfr[kt], accv[kt&3], 0, 0, 0);
    }
    asm volatile("s_waitcnt vmcnt(8)" ::: "memory");
    __builtin_amdgcn_sched_barrier(0);

    // prefetch next step's wx/alpha under the remaining MFMA work
    int tn = (t+1 < TT) ? (t+1) : t;
    size_t offn = ((size_t)tn*BB + b)*DD + e0 + rr0;
    f16x4v whn = *(const f16x4v*)(wx + offn);
    f16x4v ahn = *(const f16x4v*)(alpha + offn);

    #pragma unroll
    for (int kt=16; kt<24; ++kt){
      f16x8 a = *(const f16x8*)(Rlds + ((size_t)kt*64 + l)*8);
      accv[kt&3] = __builtin_amdgcn_mfma_f32_16x16x32_f16(a, hfr[kt], accv[kt&3], 0, 0, 0);
    }
    asm volatile("s_waitcnt vmcnt(0)" ::: "memory");
    __builtin_amdgcn_sched_barrier(0);
    #pragma unroll
    for (int kt=24; kt<32; ++kt){
      f16x8 a = *(const f16x8*)(Rlds + ((size_t)kt*64 + l)*8);
      accv[kt&3] = __builtin_amdgcn_mfma_f32_16x16x32_f16(a, hfr[kt], accv[kt&3], 0, 0, 0);
    }
    f32x4 acc = (accv[0]+accv[1]) + (accv[2]+accv[3]);

    // pointwise epilogue (same wave; no reduce, no barrier)
    f16x4v h4;
    float hs[4] = {hstate.x, hstate.y, hstate.z, hstate.w};
    #pragma unroll
    for (int r=0;r<4;++r){
      float z = acc[r] + wxv[r];
      float cand = tanhf(z);
      float hn = alv[r]*hs[r] + (1.f - alv[r])*cand;
      hs[r] = hn;
      h4[r] = (f16)hn;
    }
    hstate = (float4){hs[0], hs[1], hs[2], hs[3]};

    // release: one 8B coherent store per lane -> drain -> lane0 publishes
    f16* hw = hbuf + (size_t)((t+1) & 1) * (BB*DD) + (size_t)b*DD + e0 + rr0;
    uint2v hv = __builtin_bit_cast(uint2v, h4);
    asm volatile("global_store_dwordx2 %0, %1, off sc0 sc1"
                 :: "v"(hw), "v"(hv) : "memory");
    asm volatile("s_waitcnt vmcnt(0)" ::: "memory");
    if (l == 0)
      __hip_atomic_store(flags + j*FPAD, (unsigned)(t+1),
                         __ATOMIC_RELAXED, __HIP_MEMORY_SCOPE_AGENT);

    // off the critical path: plain hout store, rotate wx/alpha
    *(f16x4v*)(hout + ((size_t)t*BB + b)*DD + e0 + rr0) = h4;
    #pragma unroll
    for (int r=0;r<4;++r){ wxv[r] = (float)whn[r]; alv[r] = (float)ahn[r]; }
  }
}

// ---------------- host launcher ----------------
extern "C" void kernel_launch(void* const* d_in, const int* in_sizes, int n_in,
                              void* d_out, int out_size, void* d_ws, size_t ws_size,
                              hipStream_t stream)
{
  const float* x    = (const float*)d_in[0];
  const float* h0   = (const float*)d_in[1];
  const float* Wx   = (const float*)d_in[2];
  const float* R    = (const float*)d_in[3];
  const float* bias = (const float*)d_in[4];
  const float* Wd   = (const float*)d_in[5];
  const float* bd   = (const float*)d_in[6];
  const float* Aar  = (const float*)d_in[7];
  const float* Wgx  = (const float*)d_in[8];
  const float* Wgh  = (const float*)d_in[9];
  const float* bg   = (const float*)d_in[10];
  float* out = (float*)d_out;

  char* ws = (char*)d_ws;
  size_t off = 0;
  auto carve = [&](size_t bytes) -> void* {
    void* p = ws + off;
    off += (bytes + 255) & ~(size_t)255;
    return p;
  };
  f16* x16    = (f16*)carve((size_t)MM*DD*2);
  f16* Wx16   = (f16*)carve((size_t)DD*DD*2);
  f16* Wd16   = (f16*)carve((size_t)DD*DD*2);
  f16* Wgx16  = (f16*)carve((size_t)DD*DD*2);
  f16* Wgh16  = (f16*)carve((size_t)DD*DD*2);
  f16* R16    = (f16*)carve((size_t)DD*DD*2);
  f16* wx16   = (f16*)carve((size_t)MM*DD*2);
  f16* al16   = (f16*)carve((size_t)MM*DD*2);
  f16* hout16 = (f16*)carve((size_t)MM*DD*2);
  f16* hbuf   = (f16*)carve((size_t)2*BB*DD*2);
  unsigned* flags = (unsigned*)carve(64*FPAD*4);
  if (off > ws_size) return;

  cvt_kernel<<<1024, 256, 0, stream>>>(x, x16, MM*DD/4);
  dim3 g5(DD*DD/4/256, 5);
  cvt5_kernel<<<g5, 256, 0, stream>>>(Wx, Wd, Wgx, Wgh, R,
                                      Wx16, Wd16, Wgx16, Wgh16, R16);
  init_rec_kernel<<<64, 256, 0, stream>>>(h0, hbuf, flags);

  dim3 gwa(MM/128, 16);
  gemm_wa_kernel<<<gwa, 256, 0, stream>>>(x16, Wx16, Wd16, wx16, al16, bias, bd, Aar);

  rec_kernel<<<64, 64, 0, stream>>>(R16, wx16, al16, h0, hbuf, hout16, flags);

  dim3 gfin(MM/128, DD/128);
  gemm_fin_kernel<<<gfin, 256, 0, stream>>>(hout16, x16, Wgh16, Wgx16, out, bg);
}